// Round 1
// baseline (921.295 us; speedup 1.0000x reference)
//
#include <hip/hip_runtime.h>
#include <stdint.h>

#define T_TOK 8192
#define DMODEL 1024
#define FDIM 4096
#define NEXP 8
#define NROWS 16384      // T_TOK * K
#define MAXTILES 144

typedef __bf16 bf16x8 __attribute__((ext_vector_type(8)));
typedef float f32x4 __attribute__((ext_vector_type(4)));

__device__ __forceinline__ unsigned short f2bf(float f) {
  union { float f; unsigned u; } v; v.f = f;
  unsigned r = v.u + 0x7fffu + ((v.u >> 16) & 1u);
  return (unsigned short)(r >> 16);
}

// ---------------- gate: logits + top2 + softmax + expert counts ----------------
__global__ __launch_bounds__(256) void gate_kernel(
    const float* __restrict__ gx, const float* __restrict__ Wg,
    const float* __restrict__ bg, int* __restrict__ sel,
    float* __restrict__ wts, int* __restrict__ counts)
{
  int t = blockIdx.x * 4 + (threadIdx.x >> 6);
  int lane = threadIdx.x & 63;
  const float* row = gx + (size_t)t * DMODEL;
  float acc[NEXP];
#pragma unroll
  for (int e = 0; e < NEXP; ++e) acc[e] = 0.f;
  for (int d = lane; d < DMODEL; d += 64) {
    float x = row[d];
    const float* wgr = Wg + (size_t)d * NEXP;
#pragma unroll
    for (int e = 0; e < NEXP; ++e) acc[e] += x * wgr[e];
  }
#pragma unroll
  for (int off = 32; off > 0; off >>= 1) {
#pragma unroll
    for (int e = 0; e < NEXP; ++e) acc[e] += __shfl_down(acc[e], off);
  }
  if (lane == 0) {
    float lg[NEXP];
#pragma unroll
    for (int e = 0; e < NEXP; ++e) lg[e] = acc[e] + bg[e];
    int i1 = 0; float v1 = lg[0];
#pragma unroll
    for (int e = 1; e < NEXP; ++e) if (lg[e] > v1) { v1 = lg[e]; i1 = e; }
    int i2 = -1; float v2 = -3.4e38f;
#pragma unroll
    for (int e = 0; e < NEXP; ++e) if (e != i1 && lg[e] > v2) { v2 = lg[e]; i2 = e; }
    float ez = __expf(v2 - v1);           // v2 <= v1
    float s = 1.f / (1.f + ez);
    sel[t*2] = i1; sel[t*2+1] = i2;
    wts[t*2] = s;  wts[t*2+1] = ez * s;
    atomicAdd(&counts[i1], 1);
    atomicAdd(&counts[i2], 1);
  }
}

// ---------------- offsets + tile table (single thread; E=8, <=135 tiles) ------
__global__ void scan_build_kernel(const int* __restrict__ counts,
                                  int* __restrict__ offsets, int* __restrict__ ntiles,
                                  int* __restrict__ tile_e, int* __restrict__ tile_r,
                                  int* __restrict__ tile_rend)
{
  if (threadIdx.x == 0 && blockIdx.x == 0) {
    int off = 0, nt = 0;
    for (int e = 0; e < NEXP; ++e) {
      offsets[e] = off;
      int c = counts[e];
      for (int r = 0; r < c; r += 128) {
        tile_e[nt] = e; tile_r[nt] = off + r; tile_rend[nt] = off + c; ++nt;
      }
      off += c;
    }
    offsets[NEXP] = off;
    *ntiles = nt;
  }
}

// ---------------- scatter: compact per-expert token / slot lists --------------
__global__ __launch_bounds__(256) void scatter_kernel(
    const int* __restrict__ sel, int* __restrict__ cursors,
    const int* __restrict__ offsets, int* __restrict__ token_list,
    int* __restrict__ slot_list)
{
  int t = blockIdx.x * 256 + threadIdx.x;
  if (t >= T_TOK) return;
#pragma unroll
  for (int k = 0; k < 2; ++k) {
    int e = sel[t*2 + k];
    int pos = atomicAdd(&cursors[e], 1);
    int r = offsets[e] + pos;
    token_list[r] = t;
    slot_list[r] = t*2 + k;
  }
}

// ---------------- f32 -> bf16 (8 elems / thread) ------------------------------
__global__ __launch_bounds__(256) void cvt_bf16_kernel(
    const float* __restrict__ in, unsigned short* __restrict__ out, int n8)
{
  int i = blockIdx.x * 256 + threadIdx.x;
  if (i >= n8) return;
  const float4* in4 = (const float4*)in;
  float4 v0 = in4[(size_t)i*2], v1 = in4[(size_t)i*2 + 1];
  union { unsigned short u[8]; uint4 q; } r;
  r.u[0]=f2bf(v0.x); r.u[1]=f2bf(v0.y); r.u[2]=f2bf(v0.z); r.u[3]=f2bf(v0.w);
  r.u[4]=f2bf(v1.x); r.u[5]=f2bf(v1.y); r.u[6]=f2bf(v1.z); r.u[7]=f2bf(v1.w);
  ((uint4*)out)[i] = r.q;
}

// ---------------- [R][C] f32 -> [C][R] bf16 transpose (per expert) ------------
__global__ __launch_bounds__(256) void transpose_cvt_kernel(
    const float* __restrict__ in, unsigned short* __restrict__ out, int R, int C)
{
  __shared__ float tb[64][65];
  size_t ebase = (size_t)blockIdx.z * (size_t)R * (size_t)C;
  int r0 = blockIdx.y * 64, c0 = blockIdx.x * 64;
  for (int i = threadIdx.x; i < 4096; i += 256) {
    int r = i >> 6, c = i & 63;
    tb[r][c] = in[ebase + (size_t)(r0 + r) * C + (c0 + c)];
  }
  __syncthreads();
  for (int i = threadIdx.x; i < 4096; i += 256) {
    int c = i >> 6, r = i & 63;
    out[ebase + (size_t)(c0 + c) * R + (r0 + r)] = f2bf(tb[r][c]);
  }
}

// ---------------- grouped GEMM1: H = gelu(X[tok] @ W1 + b1), bf16 out ---------
// A: gathered X rows [128][K=1024], B: W1T rows (F-major) [128][1024]
// LDS tiles [128 rows][64 k] bf16, granule-XOR swizzle g^=(row&7), 16B granules.
__global__ __launch_bounds__(256) void gemm1_kernel(
    const unsigned short* __restrict__ Xb, const unsigned short* __restrict__ W1T,
    const float* __restrict__ b1, const int* __restrict__ token_list,
    const int* __restrict__ tile_e, const int* __restrict__ tile_r,
    const int* __restrict__ tile_rend, const int* __restrict__ ntiles,
    unsigned short* __restrict__ H)
{
  int bt = blockIdx.y;
  if (bt >= *ntiles) return;
  const int e = tile_e[bt];
  const int row0 = tile_r[bt];
  const int rend = tile_rend[bt];
  const int n0 = blockIdx.x * 128;

  const int tid = threadIdx.x;
  const int lane = tid & 63;
  const int wave = tid >> 6;

  __shared__ __align__(16) unsigned short sA[128 * 64];
  __shared__ __align__(16) unsigned short sB[128 * 64];

  // staging sources: G = it*256+tid -> LDS granule G (row m=G>>3, granule g=G&7)
  // linear LDS granule g holds global k-chunk (g ^ (m&7))  [pre-swizzled source]
  const unsigned short* aptr[4];
  const unsigned short* bptr[4];
#pragma unroll
  for (int it = 0; it < 4; ++it) {
    int G = it * 256 + tid;
    int m = G >> 3, g = G & 7;
    int ch = g ^ (m & 7);
    int row = row0 + m; if (row > NROWS - 1) row = NROWS - 1;
    int tok = token_list[row];
    aptr[it] = Xb + (size_t)tok * DMODEL + ch * 8;
    bptr[it] = W1T + ((size_t)e * FDIM + (n0 + m)) * DMODEL + ch * 8;
  }

  f32x4 acc[4][4] = {};
  const int wr = wave >> 1, wc = wave & 1;
  const int lm = lane & 15, lk = lane >> 4, l7 = lane & 7;
  unsigned aoff[4], boff[4];
#pragma unroll
  for (int i = 0; i < 4; ++i) aoff[i] = (unsigned)(wr*64 + i*16 + lm) * 128;
#pragma unroll
  for (int j = 0; j < 4; ++j) boff[j] = (unsigned)(wc*64 + j*16 + lm) * 128;

  for (int kt = 0; kt < DMODEL / 64; ++kt) {
    const int kbase = kt * 64;
#pragma unroll
    for (int it = 0; it < 4; ++it) {
      char* la = (char*)sA + (it*256 + wave*64) * 16;
      __builtin_amdgcn_global_load_lds(
          (const __attribute__((address_space(1))) void*)(aptr[it] + kbase),
          (__attribute__((address_space(3))) void*)la, 16, 0, 0);
    }
#pragma unroll
    for (int it = 0; it < 4; ++it) {
      char* lb = (char*)sB + (it*256 + wave*64) * 16;
      __builtin_amdgcn_global_load_lds(
          (const __attribute__((address_space(1))) void*)(bptr[it] + kbase),
          (__attribute__((address_space(3))) void*)lb, 16, 0, 0);
    }
    __syncthreads();
#pragma unroll
    for (int ks = 0; ks < 2; ++ks) {
      const unsigned kx = (unsigned)((((ks*4 + lk) ^ l7)) << 4);
      bf16x8 a[4], b[4];
#pragma unroll
      for (int i = 0; i < 4; ++i) a[i] = *(const bf16x8*)((const char*)sA + aoff[i] + kx);
#pragma unroll
      for (int j = 0; j < 4; ++j) b[j] = *(const bf16x8*)((const char*)sB + boff[j] + kx);
#pragma unroll
      for (int i = 0; i < 4; ++i)
#pragma unroll
        for (int j = 0; j < 4; ++j)
          acc[i][j] = __builtin_amdgcn_mfma_f32_16x16x32_bf16(a[i], b[j], acc[i][j], 0, 0, 0);
    }
    __syncthreads();
  }

  // epilogue: +b1, gelu(tanh approx) = v * sigmoid(1.595769*(v+0.044715 v^3)*2)
#pragma unroll
  for (int i = 0; i < 4; ++i) {
    int grb = row0 + wr*64 + i*16 + lk*4;
#pragma unroll
    for (int j = 0; j < 4; ++j) {
      int nc = n0 + wc*64 + j*16 + lm;
      float bias = b1[(size_t)e * FDIM + nc];
#pragma unroll
      for (int r = 0; r < 4; ++r) {
        int gr = grb + r;
        if (gr < rend) {
          float v = acc[i][j][r] + bias;
          float z2 = 1.5957691216f * (v + 0.044715f * v * v * v);
          float g = v / (1.f + __expf(-z2));
          H[(size_t)gr * FDIM + nc] = f2bf(g);
        }
      }
    }
  }
}

// ---------------- grouped GEMM2: y_slots[slot] = H @ W2 (f32 scatter) ---------
__global__ __launch_bounds__(256) void gemm2_kernel(
    const unsigned short* __restrict__ H, const unsigned short* __restrict__ W2T,
    const int* __restrict__ slot_list,
    const int* __restrict__ tile_e, const int* __restrict__ tile_r,
    const int* __restrict__ tile_rend, const int* __restrict__ ntiles,
    float* __restrict__ ys)
{
  int bt = blockIdx.y;
  if (bt >= *ntiles) return;
  const int e = tile_e[bt];
  const int row0 = tile_r[bt];
  const int rend = tile_rend[bt];
  const int n0 = blockIdx.x * 128;

  const int tid = threadIdx.x;
  const int lane = tid & 63;
  const int wave = tid >> 6;

  __shared__ __align__(16) unsigned short sA[128 * 64];
  __shared__ __align__(16) unsigned short sB[128 * 64];

  const unsigned short* aptr[4];
  const unsigned short* bptr[4];
#pragma unroll
  for (int it = 0; it < 4; ++it) {
    int G = it * 256 + tid;
    int m = G >> 3, g = G & 7;
    int ch = g ^ (m & 7);
    int row = row0 + m; if (row > NROWS - 1) row = NROWS - 1;
    aptr[it] = H + (size_t)row * FDIM + ch * 8;
    bptr[it] = W2T + ((size_t)e * DMODEL + (n0 + m)) * FDIM + ch * 8;
  }

  f32x4 acc[4][4] = {};
  const int wr = wave >> 1, wc = wave & 1;
  const int lm = lane & 15, lk = lane >> 4, l7 = lane & 7;
  unsigned aoff[4], boff[4];
#pragma unroll
  for (int i = 0; i < 4; ++i) aoff[i] = (unsigned)(wr*64 + i*16 + lm) * 128;
#pragma unroll
  for (int j = 0; j < 4; ++j) boff[j] = (unsigned)(wc*64 + j*16 + lm) * 128;

  for (int kt = 0; kt < FDIM / 64; ++kt) {
    const int kbase = kt * 64;
#pragma unroll
    for (int it = 0; it < 4; ++it) {
      char* la = (char*)sA + (it*256 + wave*64) * 16;
      __builtin_amdgcn_global_load_lds(
          (const __attribute__((address_space(1))) void*)(aptr[it] + kbase),
          (__attribute__((address_space(3))) void*)la, 16, 0, 0);
    }
#pragma unroll
    for (int it = 0; it < 4; ++it) {
      char* lb = (char*)sB + (it*256 + wave*64) * 16;
      __builtin_amdgcn_global_load_lds(
          (const __attribute__((address_space(1))) void*)(bptr[it] + kbase),
          (__attribute__((address_space(3))) void*)lb, 16, 0, 0);
    }
    __syncthreads();
#pragma unroll
    for (int ks = 0; ks < 2; ++ks) {
      const unsigned kx = (unsigned)((((ks*4 + lk) ^ l7)) << 4);
      bf16x8 a[4], b[4];
#pragma unroll
      for (int i = 0; i < 4; ++i) a[i] = *(const bf16x8*)((const char*)sA + aoff[i] + kx);
#pragma unroll
      for (int j = 0; j < 4; ++j) b[j] = *(const bf16x8*)((const char*)sB + boff[j] + kx);
#pragma unroll
      for (int i = 0; i < 4; ++i)
#pragma unroll
        for (int j = 0; j < 4; ++j)
          acc[i][j] = __builtin_amdgcn_mfma_f32_16x16x32_bf16(a[i], b[j], acc[i][j], 0, 0, 0);
    }
    __syncthreads();
  }

#pragma unroll
  for (int i = 0; i < 4; ++i) {
    int grb = row0 + wr*64 + i*16 + lk*4;
#pragma unroll
    for (int r = 0; r < 4; ++r) {
      int gr = grb + r;
      if (gr < rend) {
        int slot = slot_list[gr];
        float* yrow = ys + (size_t)slot * DMODEL + n0 + wc*64;
#pragma unroll
        for (int j = 0; j < 4; ++j) yrow[j*16 + lm] = acc[i][j][r];
      }
    }
  }
}

// ---------------- combine: out = sum_k w_k*(y_k + b2[e_k]) --------------------
__global__ __launch_bounds__(256) void combine_kernel(
    const float4* __restrict__ ys, const float* __restrict__ wts,
    const int* __restrict__ sel, const float* __restrict__ b2,
    float4* __restrict__ out)
{
  int i = blockIdx.x * 256 + threadIdx.x;   // over T*D/4
  int t = i >> 8, d4 = i & 255;
  float w0 = wts[t*2], w1 = wts[t*2 + 1];
  int e0 = sel[t*2], e1 = sel[t*2 + 1];
  float4 y0 = ys[(size_t)(t*2) * 256 + d4];
  float4 y1 = ys[(size_t)(t*2 + 1) * 256 + d4];
  const float4* b24 = (const float4*)b2;
  float4 c0 = b24[e0 * 256 + d4];
  float4 c1 = b24[e1 * 256 + d4];
  float4 o;
  o.x = w0 * (y0.x + c0.x) + w1 * (y1.x + c1.x);
  o.y = w0 * (y0.y + c0.y) + w1 * (y1.y + c1.y);
  o.z = w0 * (y0.z + c0.z) + w1 * (y1.z + c1.z);
  o.w = w0 * (y0.w + c0.w) + w1 * (y1.w + c1.w);
  out[(size_t)t * 256 + d4] = o;
}

// ---------------- host ---------------------------------------------------------
extern "C" void kernel_launch(void* const* d_in, const int* in_sizes, int n_in,
                              void* d_out, int out_size, void* d_ws, size_t ws_size,
                              hipStream_t stream)
{
  const float* gate_inputs = (const float*)d_in[0];
  const float* inputs      = (const float*)d_in[1];
  const float* Wg          = (const float*)d_in[2];
  const float* bg          = (const float*)d_in[3];
  const float* w1          = (const float*)d_in[4];
  const float* b1          = (const float*)d_in[5];
  const float* w2          = (const float*)d_in[6];
  const float* b2          = (const float*)d_in[7];
  float* out = (float*)d_out;

  char* ws = (char*)d_ws;
  size_t o = 0;
  auto carve = [&](size_t bytes) { void* p = ws + o; o += (bytes + 255) & ~(size_t)255; return p; };
  unsigned short* Xb  = (unsigned short*)carve((size_t)T_TOK * DMODEL * 2);
  unsigned short* W1T = (unsigned short*)carve((size_t)NEXP * FDIM * DMODEL * 2);
  unsigned short* W2T = (unsigned short*)carve((size_t)NEXP * DMODEL * FDIM * 2);
  unsigned short* H   = (unsigned short*)carve((size_t)NROWS * FDIM * 2);
  float* ys           = (float*)carve((size_t)NROWS * DMODEL * 4);
  int*   sel          = (int*)carve((size_t)NROWS * 4);
  float* wts          = (float*)carve((size_t)NROWS * 4);
  int*   token_list   = (int*)carve((size_t)(NROWS + 256) * 4);
  int*   slot_list    = (int*)carve((size_t)(NROWS + 256) * 4);
  int*   ctrl         = (int*)carve(4096);
  int* counts  = ctrl;            // 8
  int* cursors = ctrl + 8;        // 8
  int* offsets = ctrl + 16;       // 9
  int* ntiles  = ctrl + 28;       // 1
  int* tile_e  = ctrl + 32;
  int* tile_r  = ctrl + 32 + MAXTILES;
  int* tile_rend = ctrl + 32 + 2 * MAXTILES;

  hipMemsetAsync(counts, 0, 64, stream);  // counts + cursors

  gate_kernel<<<T_TOK / 4, 256, 0, stream>>>(gate_inputs, Wg, bg, sel, wts, counts);
  scan_build_kernel<<<1, 64, 0, stream>>>(counts, offsets, ntiles, tile_e, tile_r, tile_rend);
  scatter_kernel<<<T_TOK / 256, 256, 0, stream>>>(sel, cursors, offsets, token_list, slot_list);
  cvt_bf16_kernel<<<(T_TOK * DMODEL / 8) / 256, 256, 0, stream>>>(inputs, Xb, T_TOK * DMODEL / 8);
  transpose_cvt_kernel<<<dim3(FDIM / 64, DMODEL / 64, NEXP), 256, 0, stream>>>(w1, W1T, DMODEL, FDIM);
  transpose_cvt_kernel<<<dim3(DMODEL / 64, FDIM / 64, NEXP), 256, 0, stream>>>(w2, W2T, FDIM, DMODEL);
  gemm1_kernel<<<dim3(FDIM / 128, MAXTILES), 256, 0, stream>>>(Xb, W1T, b1, token_list,
      tile_e, tile_r, tile_rend, ntiles, H);
  gemm2_kernel<<<dim3(DMODEL / 128, MAXTILES), 256, 0, stream>>>(H, W2T, slot_list,
      tile_e, tile_r, tile_rend, ntiles, ys);
  combine_kernel<<<(T_TOK * DMODEL / 4) / 256, 256, 0, stream>>>((const float4*)ys, wts, sel, b2, (float4*)out);
}